// Round 1
// baseline (470.162 us; speedup 1.0000x reference)
//
#include <hip/hip_runtime.h>
#include <hip/hip_bf16.h>
#include <cstdint>

// EdgeFrontierPolicy: E=400000 edges (divisible by 64), G=64 graphs, H=256.
// Pipeline: prep (pack weights bf16 + folds + mask-dtype detect) -> edge kernel
// (LN + 2x MFMA GEMM + logits + pooled atomics) -> stop kernel.

typedef __bf16 bf16x8 __attribute__((ext_vector_type(8)));
typedef float  f32x4  __attribute__((ext_vector_type(4)));

__device__ __forceinline__ float gelu_f(float x) {
  return 0.5f * x * (1.0f + erff(x * 0.7071067811865476f));
}

// ---------------------------------------------------------------------------
// Prep: pack W1 (ln1_g folded) and W2 into MFMA-B fragment order, bf16.
// Packed layout: out[((kt*16+nt)*64 + lane)*8 + i] = W[kt*32 + 8*(lane>>4)+i][nt*16 + (lane&15)]
// so a B-fragment is a contiguous 16B per lane (ds_read_b128 after LDS staging).
__global__ void prep_pack(const float* __restrict__ W1, const float* __restrict__ W2,
                          const float* __restrict__ ln1g,
                          __bf16* __restrict__ W1p, __bf16* __restrict__ W2p) {
  int gid = blockIdx.x * blockDim.x + threadIdx.x;   // 16384 threads
  int m  = gid >> 13;          // 0: W1, 1: W2
  int b  = (gid >> 6) & 127;   // (kt*16+nt)
  int l  = gid & 63;
  int kt = b >> 4, nt = b & 15;
  int k0 = kt * 32 + ((l >> 4) << 3);
  int n  = nt * 16 + (l & 15);
  const float* W = m ? W2 : W1;
  bf16x8 v;
#pragma unroll
  for (int i = 0; i < 8; ++i) {
    int k = k0 + i;
    float wv = W[k * 256 + n];
    if (!m) wv *= ln1g[k];
    v[i] = (__bf16)wv;
  }
  __bf16* dst = m ? W2p : W1p;
  *(bf16x8*)(dst + (size_t)(b * 64 + l) * 8) = v;
}

// C0[n] = b1[n] + sum_k ln1b[k]*W1[k][n];  GW6/GW7 = ln1g[256/257]*W1[256/257][n].
// Also detect selected_mask storage format (int32 vs byte).
__global__ void prep_vec(const float* __restrict__ W1, const float* __restrict__ ln1g,
                         const float* __restrict__ ln1b, const float* __restrict__ b1,
                         const unsigned* __restrict__ smask_words,
                         float* __restrict__ C0, float* __restrict__ GW6,
                         float* __restrict__ GW7, int* __restrict__ maskIsByte) {
  int t = threadIdx.x;  // 256
  float c = b1[t];
  for (int k = 0; k < 258; ++k) c += ln1b[k] * W1[k * 256 + t];
  C0[t]  = c;
  GW6[t] = ln1g[256] * W1[256 * 256 + t];
  GW7[t] = ln1g[257] * W1[257 * 256 + t];
  if (t == 0) {
    int big = 0;
    for (int i = 0; i < 64; ++i) { if (smask_words[i] > 1u) big = 1; }
    *maskIsByte = big;  // byte-packed bool => some 4-byte word > 1 (P(miss)~1e-30)
  }
}

// ---------------------------------------------------------------------------
// Edge kernel: 64 edges per block, 256 threads (4 waves).
#define EPB 64

__global__ __launch_bounds__(256, 2) void edge_kernel(
    const float* __restrict__ tok, const int* __restrict__ ebatch,
    const unsigned char* __restrict__ smaskB,
    const int* __restrict__ eheads, const int* __restrict__ etails,
    const int* __restrict__ curtail,
    const __bf16* __restrict__ W1p, const __bf16* __restrict__ W2p,
    const float* __restrict__ C0v, const float* __restrict__ GW6v,
    const float* __restrict__ GW7v, const float* __restrict__ b2v,
    const float* __restrict__ selwv, const float* __restrict__ selbv,
    const int* __restrict__ maskFlag,
    float* __restrict__ outLogits, float* __restrict__ pooledAcc,
    float* __restrict__ cnts) {
  __shared__ __align__(16) char As_[64 * 512];       // A tile, bf16, XOR-swizzled rows
  __shared__ __align__(16) char Bs_[2][16384];       // B k-step tiles (32x256 bf16), dbuf
  __shared__ float sC0[256], sGW6[256], sGW7[256], sB2[256], sSelw[256];
  __shared__ float sAux0[64], sAux1[64], sFront[64];
  __shared__ int sG[64];

  const int t = threadIdx.x;
  const int w = t >> 6;       // wave id: owns edges [w*16, w*16+16)
  const int l = t & 63;
  const int base = blockIdx.x * EPB;

  // ---- P0: flags + stage small vectors ----
  sC0[t] = C0v[t]; sGW6[t] = GW6v[t]; sGW7[t] = GW7v[t];
  sB2[t] = b2v[t]; sSelw[t] = selwv[t];
  if (t < 64) {
    int ge = base + t;
    int g  = ebatch[ge];
    int mb = *maskFlag;
    int mv = mb ? (int)smaskB[ge] : ((const int*)smaskB)[ge];
    int cand = (mv == 0);
    int cur  = curtail[g];
    int fr   = cand && ((eheads[ge] == cur) || (etails[ge] == cur));
    sAux0[t] = (float)cand; sAux1[t] = (float)fr; sFront[t] = (float)fr; sG[t] = g;
  }
  __syncthreads();

  // counts: run-length over sorted graph ids (1-2 distinct per block typically)
  if (t == 0) {
    int cg = sG[0]; float run = 1.f;
    for (int e = 1; e < 64; ++e) {
      int g = sG[e];
      if (g == cg) run += 1.f;
      else { atomicAdd(&cnts[cg], run); cg = g; run = 1.f; }
    }
    atomicAdd(&cnts[cg], run);
  }

  // ---- P1: LayerNorm over 258 (256 tokens + 2 aux), write z (g,b folded away) ----
  {
    const int e = t >> 2, q = t & 3;          // 4 threads per edge
    const float* rp = tok + (size_t)(base + e) * 256 + q * 4;
    float4 v[16];
    float s = 0.f, s2 = 0.f;
#pragma unroll
    for (int j = 0; j < 16; ++j) {
      v[j] = *(const float4*)(rp + j * 16);
      s  += v[j].x + v[j].y + v[j].z + v[j].w;
      s2 += v[j].x * v[j].x + v[j].y * v[j].y + v[j].z * v[j].z + v[j].w * v[j].w;
    }
    if (q == 0) { float a0 = sAux0[e], a1 = sAux1[e]; s += a0 + a1; s2 += a0 + a1; }
    s  += __shfl_xor(s, 1);  s  += __shfl_xor(s, 2);
    s2 += __shfl_xor(s2, 1); s2 += __shfl_xor(s2, 2);
    const float mean = s * (1.0f / 258.0f);
    const float var  = s2 * (1.0f / 258.0f) - mean * mean;
    const float rstd = rsqrtf(var + 1e-5f);
    const unsigned sw = (unsigned)(e & 7) << 4;   // T2 XOR swizzle (16B granules)
#pragma unroll
    for (int j = 0; j < 16; ++j) {
      union { __bf16 h[4]; uint2 u; } cv;
      cv.h[0] = (__bf16)((v[j].x - mean) * rstd);
      cv.h[1] = (__bf16)((v[j].y - mean) * rstd);
      cv.h[2] = (__bf16)((v[j].z - mean) * rstd);
      cv.h[3] = (__bf16)((v[j].w - mean) * rstd);
      unsigned off = (unsigned)(q * 8 + j * 32);
      *(uint2*)(As_ + e * 512 + (off ^ sw)) = cv.u;
    }
    if (q == 0) {  // overwrite with normalized aux (read by acc-init after barrier)
      sAux0[e] = (sAux0[e] - mean) * rstd;
      sAux1[e] = (sAux1[e] - mean) * rstd;
    }
  }

  // stage W1 k-step 0 (packed layout is linear: 16KB contiguous per k-step)
  {
    const char* g0 = (const char*)W1p + t * 16;
    uint4 r0 = *(const uint4*)(g0);
    uint4 r1 = *(const uint4*)(g0 + 4096);
    uint4 r2 = *(const uint4*)(g0 + 8192);
    uint4 r3 = *(const uint4*)(g0 + 12288);
    char* wb = Bs_[0] + t * 16;
    *(uint4*)(wb) = r0; *(uint4*)(wb + 4096) = r1;
    *(uint4*)(wb + 8192) = r2; *(uint4*)(wb + 12288) = r3;
  }
  __syncthreads();

  // ---- acc init: C0 + rank-2 aux update (the 2 extra K columns) ----
  f32x4 acc[16];
  {
    float za0[4], za1[4];
#pragma unroll
    for (int i = 0; i < 4; ++i) {
      int edge = (w << 4) + ((l >> 4) << 2) + i;
      za0[i] = sAux0[edge]; za1[i] = sAux1[edge];
    }
#pragma unroll
    for (int nf = 0; nf < 16; ++nf) {
      int col = (nf << 4) + (l & 15);
      float c0 = sC0[col], w6 = sGW6[col], w7 = sGW7[col];
#pragma unroll
      for (int i = 0; i < 4; ++i) acc[nf][i] = c0 + za0[i] * w6 + za1[i] * w7;
    }
  }

  const int rowA = (w << 4) + (l & 15);
  const unsigned swA = (unsigned)(rowA & 7) << 4;
  const unsigned slA = (unsigned)((l >> 4) << 4);

  // ---- GEMM1: h1 = zln @ (g*W1),  K=256 in 8 steps of 32 ----
#pragma unroll
  for (int kt = 0; kt < 8; ++kt) {
    uint4 r0, r1, r2, r3;
    if (kt < 7) {
      const char* gp = (const char*)W1p + (kt + 1) * 16384 + t * 16;
      r0 = *(const uint4*)(gp);        r1 = *(const uint4*)(gp + 4096);
      r2 = *(const uint4*)(gp + 8192); r3 = *(const uint4*)(gp + 12288);
    }
    const char* bb = Bs_[kt & 1];
    bf16x8 a = *(const bf16x8*)(As_ + rowA * 512 + ((((unsigned)kt << 6) | slA) ^ swA));
#pragma unroll
    for (int nf = 0; nf < 16; ++nf) {
      bf16x8 b = *(const bf16x8*)(bb + (nf << 10) + (l << 4));
      acc[nf] = __builtin_amdgcn_mfma_f32_16x16x32_bf16(a, b, acc[nf], 0, 0, 0);
    }
    if (kt < 7) {
      char* wb = Bs_[(kt + 1) & 1] + t * 16;
      *(uint4*)(wb) = r0; *(uint4*)(wb + 4096) = r1;
      *(uint4*)(wb + 8192) = r2; *(uint4*)(wb + 12288) = r3;
      __syncthreads();
    }
  }

  // ---- epilogue 1: gelu, write h1 (bf16) back to A tile (wave-private rows) ----
#pragma unroll
  for (int nf = 0; nf < 16; ++nf) {
    int col = (nf << 4) + (l & 15);
#pragma unroll
    for (int i = 0; i < 4; ++i) {
      int row = (w << 4) + ((l >> 4) << 2) + i;
      float hv = gelu_f(acc[nf][i]);
      unsigned off = ((unsigned)(col * 2)) ^ ((unsigned)(row & 7) << 4);
      *(__bf16*)(As_ + row * 512 + off) = (__bf16)hv;
    }
  }
  // stage W2 k-step 0 (Bs_[0] free: its last readers finished before kt=6 barrier)
  {
    const char* g0 = (const char*)W2p + t * 16;
    uint4 r0 = *(const uint4*)(g0);
    uint4 r1 = *(const uint4*)(g0 + 4096);
    uint4 r2 = *(const uint4*)(g0 + 8192);
    uint4 r3 = *(const uint4*)(g0 + 12288);
    char* wb = Bs_[0] + t * 16;
    *(uint4*)(wb) = r0; *(uint4*)(wb + 4096) = r1;
    *(uint4*)(wb + 8192) = r2; *(uint4*)(wb + 12288) = r3;
  }
  __syncthreads();

  // ---- GEMM2: h2 = h1 @ W2 ----
#pragma unroll
  for (int nf = 0; nf < 16; ++nf) {
    float bb2 = sB2[(nf << 4) + (l & 15)];
#pragma unroll
    for (int i = 0; i < 4; ++i) acc[nf][i] = bb2;
  }
#pragma unroll
  for (int kt = 0; kt < 8; ++kt) {
    uint4 r0, r1, r2, r3;
    if (kt < 7) {
      const char* gp = (const char*)W2p + (kt + 1) * 16384 + t * 16;
      r0 = *(const uint4*)(gp);        r1 = *(const uint4*)(gp + 4096);
      r2 = *(const uint4*)(gp + 8192); r3 = *(const uint4*)(gp + 12288);
    }
    const char* bb = Bs_[kt & 1];
    bf16x8 a = *(const bf16x8*)(As_ + rowA * 512 + ((((unsigned)kt << 6) | slA) ^ swA));
#pragma unroll
    for (int nf = 0; nf < 16; ++nf) {
      bf16x8 b = *(const bf16x8*)(bb + (nf << 10) + (l << 4));
      acc[nf] = __builtin_amdgcn_mfma_f32_16x16x32_bf16(a, b, acc[nf], 0, 0, 0);
    }
    if (kt < 7) {
      char* wb = Bs_[(kt + 1) & 1] + t * 16;
      *(uint4*)(wb) = r0; *(uint4*)(wb + 4096) = r1;
      *(uint4*)(wb + 8192) = r2; *(uint4*)(wb + 12288) = r3;
      __syncthreads();
    }
  }

  // ---- epilogue 2: gelu -> logits + pooled ----
#pragma unroll
  for (int nf = 0; nf < 16; ++nf)
#pragma unroll
    for (int i = 0; i < 4; ++i) acc[nf][i] = gelu_f(acc[nf][i]);

  // selection logits: dot with sel_w, reduce across the 16 col-lanes
  {
    float part[4] = {0.f, 0.f, 0.f, 0.f};
#pragma unroll
    for (int nf = 0; nf < 16; ++nf) {
      float wv = sSelw[(nf << 4) + (l & 15)];
#pragma unroll
      for (int i = 0; i < 4; ++i) part[i] += acc[nf][i] * wv;
    }
#pragma unroll
    for (int i = 0; i < 4; ++i) {
      part[i] += __shfl_xor(part[i], 1);
      part[i] += __shfl_xor(part[i], 2);
      part[i] += __shfl_xor(part[i], 4);
      part[i] += __shfl_xor(part[i], 8);
    }
    if ((l & 15) == 0) {
      float sb = selbv[0];
#pragma unroll
      for (int i = 0; i < 4; ++i) {
        int eloc = (w << 4) + ((l >> 4) << 2) + i;
        outLogits[base + eloc] = part[i] + sb + 0.5f * sFront[eloc];
      }
    }
  }

  // pooled: segment-sum h2 by graph (sorted => usually wave-uniform)
  {
    int g0 = sG[w << 4], g15 = sG[(w << 4) + 15];
    if (g0 == g15) {
#pragma unroll
      for (int nf = 0; nf < 16; ++nf) {
        float sv = acc[nf][0] + acc[nf][1] + acc[nf][2] + acc[nf][3];
        sv += __shfl_xor(sv, 16);
        sv += __shfl_xor(sv, 32);
        if (l < 16) atomicAdd(&pooledAcc[g0 * 256 + (nf << 4) + l], sv);
      }
    } else {
#pragma unroll
      for (int nf = 0; nf < 16; ++nf) {
        int col = (nf << 4) + (l & 15);
#pragma unroll
        for (int i = 0; i < 4; ++i) {
          int eloc = (w << 4) + ((l >> 4) << 2) + i;
          atomicAdd(&pooledAcc[sG[eloc] * 256 + col], acc[nf][i]);
        }
      }
    }
  }
}

// ---------------------------------------------------------------------------
// Stop head: one block per graph.
__global__ __launch_bounds__(256) void stop_kernel(
    const float* __restrict__ pooledAcc, const float* __restrict__ cnts,
    const float* __restrict__ qtok,
    const float* __restrict__ ln2g, const float* __restrict__ ln2b,
    const float* __restrict__ sW1, const float* __restrict__ sb1,
    const float* __restrict__ sW2, const float* __restrict__ sb2,
    float* __restrict__ outStop, float* __restrict__ outPooled) {
  __shared__ float sIn[512], sLn[512], sRed[8];
  const int t = threadIdx.x, g = blockIdx.x;
  const int w = t >> 6, l = t & 63;
  float c = fmaxf(cnts[g], 1.0f);
  float p = pooledAcc[g * 256 + t] / c;
  outPooled[g * 256 + t] = p;
  sIn[t] = p;
  sIn[256 + t] = qtok[g * 256 + t];
  __syncthreads();
  float a = sIn[t], b = sIn[256 + t];
  float s = a + b, s2 = a * a + b * b;
#pragma unroll
  for (int m = 1; m < 64; m <<= 1) { s += __shfl_xor(s, m); s2 += __shfl_xor(s2, m); }
  if (l == 0) { sRed[w] = s; sRed[4 + w] = s2; }
  __syncthreads();
  s  = sRed[0] + sRed[1] + sRed[2] + sRed[3];
  s2 = sRed[4] + sRed[5] + sRed[6] + sRed[7];
  const float mean = s * (1.0f / 512.0f);
  const float var  = s2 * (1.0f / 512.0f) - mean * mean;
  const float rstd = rsqrtf(var + 1e-5f);
  sLn[t]       = (a - mean) * rstd * ln2g[t] + ln2b[t];
  sLn[256 + t] = (b - mean) * rstd * ln2g[256 + t] + ln2b[256 + t];
  __syncthreads();
  float accv = sb1[t];
#pragma unroll 8
  for (int k = 0; k < 512; ++k) accv += sLn[k] * sW1[k * 256 + t];
  float u = gelu_f(accv);
  float part = u * sW2[t];
#pragma unroll
  for (int m = 1; m < 64; m <<= 1) part += __shfl_xor(part, m);
  if (l == 0) sRed[w] = part;
  __syncthreads();
  if (t == 0) outStop[g] = sRed[0] + sRed[1] + sRed[2] + sRed[3] + sb2[0];
}

// ---------------------------------------------------------------------------
extern "C" void kernel_launch(void* const* d_in, const int* in_sizes, int n_in,
                              void* d_out, int out_size, void* d_ws, size_t ws_size,
                              hipStream_t stream) {
  const float* tok   = (const float*)d_in[0];
  const float* qtok  = (const float*)d_in[1];
  const int* ebatch  = (const int*)d_in[2];
  const void* smask  = d_in[3];
  const int* eheads  = (const int*)d_in[4];
  const int* etails  = (const int*)d_in[5];
  const int* curtail = (const int*)d_in[6];
  const float* ln1g  = (const float*)d_in[7];
  const float* ln1b  = (const float*)d_in[8];
  const float* W1    = (const float*)d_in[9];
  const float* b1    = (const float*)d_in[10];
  const float* W2    = (const float*)d_in[11];
  const float* b2    = (const float*)d_in[12];
  const float* selw  = (const float*)d_in[13];
  const float* selb  = (const float*)d_in[14];
  const float* ln2g  = (const float*)d_in[15];
  const float* ln2b  = (const float*)d_in[16];
  const float* sW1   = (const float*)d_in[17];
  const float* sb1   = (const float*)d_in[18];
  const float* sW2   = (const float*)d_in[19];
  const float* sb2   = (const float*)d_in[20];

  const int E = in_sizes[2];            // 400000 (divisible by 64)
  const int G = in_sizes[1] / 256;      // 64

  char* ws = (char*)d_ws;
  __bf16* W1p   = (__bf16*)(ws);                 // 131072 B
  __bf16* W2p   = (__bf16*)(ws + 131072);        // 131072 B
  float*  C0    = (float*)(ws + 262144);         // 1024 B
  float*  GW6   = (float*)(ws + 263168);         // 1024 B
  float*  GW7   = (float*)(ws + 264192);         // 1024 B
  float*  pooled= (float*)(ws + 265216);         // 65536 B
  float*  cnts  = (float*)(ws + 330752);         // 256 B
  int*    mflag = (int*)(ws + 331008);           // 4 B
  (void)ws_size; (void)n_in; (void)out_size;

  hipMemsetAsync(ws + 265216, 0, 65536 + 256, stream);  // pooled + counts

  prep_pack<<<64, 256, 0, stream>>>(W1, W2, ln1g, W1p, W2p);
  prep_vec<<<1, 256, 0, stream>>>(W1, ln1g, ln1b, b1, (const unsigned*)smask,
                                  C0, GW6, GW7, mflag);
  edge_kernel<<<E / EPB, 256, 0, stream>>>(
      tok, ebatch, (const unsigned char*)smask, eheads, etails, curtail,
      W1p, W2p, C0, GW6, GW7, b2, selw, selb, mflag,
      (float*)d_out, pooled, cnts);
  stop_kernel<<<G, 256, 0, stream>>>(pooled, cnts, qtok, ln2g, ln2b,
                                     sW1, sb1, sW2, sb2,
                                     (float*)d_out + E, (float*)d_out + E + G);
}

// Round 2
// 433.318 us; speedup vs baseline: 1.0850x; 1.0850x over previous
//
#include <hip/hip_runtime.h>
#include <hip/hip_bf16.h>
#include <cstdint>

// EdgeFrontierPolicy: E=400000, G=64, H=256.
// prep (pack W bf16, folds) -> edge kernel (LN + 2 MFMA GEMMs, M=128/block,
// triple-buffered global_load_lds B-staging, counted vmcnt) -> stop kernel.

typedef __bf16 bf16x8 __attribute__((ext_vector_type(8)));
typedef float  f32x4  __attribute__((ext_vector_type(4)));

typedef __attribute__((address_space(1))) const char gas_char;
typedef __attribute__((address_space(3))) char las_char;

// gelu tanh-form: x*sigmoid(2*0.79788456*(x+0.044715x^3)); exp via v_exp_f32.
// max abs err vs exact-erf gelu ~5e-4 over |x|<3 -> logit err ~1e-4 (thr 1e-2).
__device__ __forceinline__ float gelu_f(float x) {
  float x2 = x * x;
  float t1 = __builtin_fmaf(0.1029444f, x2, 2.3022078f);  // (2*log2e)*0.79788456*{0.044715, 1}
  float a  = x * t1;
  float e;
  asm("v_exp_f32 %0, %1" : "=v"(e) : "v"(a));
  float r;
  asm("v_rcp_f32 %0, %1" : "=v"(r) : "v"(e + 1.0f));
  return x - x * r;   // x * (1 - 1/(1+2^a)) = x*sigmoid(a*ln2... a scaled already)
}

// ---------------------------------------------------------------------------
// Pack W1 (ln1_g folded) / W2 into MFMA-B fragment order, bf16.
// out[((kt*16+nt)*64 + lane)*8 + i] = W[kt*32 + 8*(lane>>4)+i][nt*16 + (lane&15)]
__global__ void prep_pack(const float* __restrict__ W1, const float* __restrict__ W2,
                          const float* __restrict__ ln1g,
                          __bf16* __restrict__ W1p, __bf16* __restrict__ W2p) {
  int gid = blockIdx.x * blockDim.x + threadIdx.x;   // 16384 threads
  int m  = gid >> 13;
  int b  = (gid >> 6) & 127;
  int l  = gid & 63;
  int kt = b >> 4, nt = b & 15;
  int k0 = kt * 32 + ((l >> 4) << 3);
  int n  = nt * 16 + (l & 15);
  const float* W = m ? W2 : W1;
  bf16x8 v;
#pragma unroll
  for (int i = 0; i < 8; ++i) {
    int k = k0 + i;
    float wv = W[k * 256 + n];
    if (!m) wv *= ln1g[k];
    v[i] = (__bf16)wv;
  }
  __bf16* dst = m ? W2p : W1p;
  *(bf16x8*)(dst + (size_t)(b * 64 + l) * 8) = v;
}

__global__ void prep_vec(const float* __restrict__ W1, const float* __restrict__ ln1g,
                         const float* __restrict__ ln1b, const float* __restrict__ b1,
                         const unsigned* __restrict__ smask_words,
                         float* __restrict__ C0, float* __restrict__ GW6,
                         float* __restrict__ GW7, int* __restrict__ maskIsByte) {
  int t = threadIdx.x;  // 256
  float c = b1[t];
#pragma unroll 4
  for (int k = 0; k < 258; ++k) c += ln1b[k] * W1[k * 256 + t];
  C0[t]  = c;
  GW6[t] = ln1g[256] * W1[256 * 256 + t];
  GW7[t] = ln1g[257] * W1[257 * 256 + t];
  if (t == 0) {
    int big = 0;
    for (int i = 0; i < 64; ++i) { if (smask_words[i] > 1u) big = 1; }
    *maskIsByte = big;
  }
}

// ---------------------------------------------------------------------------
#define EPB 128

__device__ __forceinline__ void stage2(const char* gsrc, char* ldst) {
  __builtin_amdgcn_global_load_lds((gas_char*)gsrc, (las_char*)ldst, 16, 0, 0);
  __builtin_amdgcn_global_load_lds((gas_char*)(gsrc + 1024), (las_char*)(ldst + 1024), 16, 0, 0);
}

// 8 K-steps of 32, triple-buffered B, one barrier per K-step, counted vmcnt.
// Assumes: stage(0)->Bb0 and stage(1)->Bb1 already issued (and possibly drained).
__device__ __forceinline__ void gemm8(const char* __restrict__ Wp,
                                      char* Bb0, char* Bb1, char* Bb2,
                                      const char* aBase, unsigned swA, unsigned gA,
                                      int bOff, int woff, int l16, f32x4 (&acc)[4][4]) {
#pragma unroll
  for (int kt = 0; kt < 8; ++kt) {
    if (kt < 7) asm volatile("s_waitcnt vmcnt(2)" ::: "memory");
    else        asm volatile("s_waitcnt vmcnt(0)" ::: "memory");
    __builtin_amdgcn_s_barrier();
    char* bufs[3] = {Bb0, Bb1, Bb2};
    if (kt < 6) stage2(Wp + (kt + 2) * 16384 + woff + l16, bufs[(kt + 2) % 3] + woff);
    const char* bb = bufs[kt % 3];
    bf16x8 av[4], bv[4];
#pragma unroll
    for (int rf = 0; rf < 4; ++rf)
      av[rf] = *(const bf16x8*)(aBase + rf * 8192 + (((unsigned)(kt * 64) + gA) ^ swA));
#pragma unroll
    for (int cf = 0; cf < 4; ++cf)
      bv[cf] = *(const bf16x8*)(bb + bOff + (cf << 10));
#pragma unroll
    for (int rf = 0; rf < 4; ++rf)
#pragma unroll
      for (int cf = 0; cf < 4; ++cf)
        acc[rf][cf] = __builtin_amdgcn_mfma_f32_16x16x32_bf16(av[rf], bv[cf], acc[rf][cf], 0, 0, 0);
  }
  __builtin_amdgcn_s_barrier();  // all reads of As_/B bufs done before caller overwrites
}

__global__ __launch_bounds__(512, 2) void edge_kernel(
    const float* __restrict__ tok, const int* __restrict__ ebatch,
    const unsigned char* __restrict__ smaskB,
    const int* __restrict__ eheads, const int* __restrict__ etails,
    const int* __restrict__ curtail,
    const __bf16* __restrict__ W1p, const __bf16* __restrict__ W2p,
    const float* __restrict__ C0v, const float* __restrict__ GW6v,
    const float* __restrict__ GW7v, const float* __restrict__ b2v,
    const float* __restrict__ selwv, const float* __restrict__ selbv,
    const int* __restrict__ maskFlag,
    float* __restrict__ outLogits, float* __restrict__ pooledAcc,
    float* __restrict__ cnts) {
  __shared__ __align__(16) char As_[128 * 512];                       // 64KB A tile (XOR-swizzled rows)
  __shared__ __align__(16) char Bs0_[16384], Bs1_[16384], Bs2_[16384];// 48KB B triple-buffer
  __shared__ float sZa0[128], sZa1[128], sFront[128];
  __shared__ float sLog[128][4];
  __shared__ int sG[128];

  const int t = threadIdx.x;
  const int w = t >> 6, l = t & 63;
  const int wr = w >> 2, wc = w & 3;
  const int base = blockIdx.x * EPB;
  const int l16 = l << 4;
  const int woff = __builtin_amdgcn_readfirstlane(w << 11);  // wave's 2KB share

  // pre-stage W1 k-steps 0,1 (drained by the LN __syncthreads; free overlap)
  stage2((const char*)W1p + woff + l16, Bs0_ + woff);
  stage2((const char*)W1p + 16384 + woff + l16, Bs1_ + woff);

  // ---- flags ----
  if (t < 128) {
    int ge = base + t;
    int g  = ebatch[ge];
    int mb = *maskFlag;
    int mv = mb ? (int)smaskB[ge] : ((const int*)smaskB)[ge];
    int cand = (mv == 0);
    int cur  = curtail[g];
    int fr   = cand && ((eheads[ge] == cur) || (etails[ge] == cur));
    sZa0[t] = (float)cand; sZa1[t] = (float)fr; sFront[t] = (float)fr; sG[t] = g;
  }
  __syncthreads();

  if (t == 0) {  // counts: run-length over sorted graph ids
    int cg = sG[0]; float run = 1.f;
    for (int e = 1; e < EPB; ++e) {
      int g = sG[e];
      if (g == cg) run += 1.f;
      else { atomicAdd(&cnts[cg], run); cg = g; run = 1.f; }
    }
    atomicAdd(&cnts[cg], run);
  }

  // ---- LayerNorm over 258 (4 threads/edge), write bf16 A tile swizzled ----
  {
    const int e = t >> 2, q = t & 3;
    const float* rp = tok + (size_t)(base + e) * 256 + q * 4;
    float4 v[16];
    float s = 0.f, s2 = 0.f;
#pragma unroll
    for (int j = 0; j < 16; ++j) {
      v[j] = *(const float4*)(rp + j * 16);
      s  += v[j].x + v[j].y + v[j].z + v[j].w;
      s2 += v[j].x * v[j].x + v[j].y * v[j].y + v[j].z * v[j].z + v[j].w * v[j].w;
    }
    float a0 = 0.f, a1 = 0.f;
    if (q == 0) { a0 = sZa0[e]; a1 = sZa1[e]; s += a0 + a1; s2 += a0 + a1; }  // 0/1 flags: x==x^2
    s  += __shfl_xor(s, 1);  s  += __shfl_xor(s, 2);
    s2 += __shfl_xor(s2, 1); s2 += __shfl_xor(s2, 2);
    const float mean = s * (1.0f / 258.0f);
    const float var  = s2 * (1.0f / 258.0f) - mean * mean;
    const float rstd = rsqrtf(var + 1e-5f);
    const unsigned sw = (unsigned)(e & 7) << 4;
#pragma unroll
    for (int j = 0; j < 16; ++j) {
      union { __bf16 h[4]; uint2 u; } cv;
      cv.h[0] = (__bf16)((v[j].x - mean) * rstd);
      cv.h[1] = (__bf16)((v[j].y - mean) * rstd);
      cv.h[2] = (__bf16)((v[j].z - mean) * rstd);
      cv.h[3] = (__bf16)((v[j].w - mean) * rstd);
      unsigned off = (unsigned)(q * 8 + j * 32);
      *(uint2*)(As_ + e * 512 + (off ^ sw)) = cv.u;
    }
    if (q == 0) {
      sZa0[e] = (a0 - mean) * rstd;
      sZa1[e] = (a1 - mean) * rstd;
    }
  }
  __syncthreads();   // LN writes + normalized aux visible (drains pre-staged W1 too)

  // ---- per-thread constants + acc init (C0 + rank-2 aux) ----
  const int rA = l & 15;
  const int r0 = (l >> 4) << 2;
  float c0r[4], w6r[4], w7r[4], b2r[4], lwr[4];
  const float selbr = selbv[0];
#pragma unroll
  for (int cf = 0; cf < 4; ++cf) {
    int col = wc * 64 + cf * 16 + rA;
    c0r[cf] = C0v[col]; w6r[cf] = GW6v[col]; w7r[cf] = GW7v[col];
    b2r[cf] = b2v[col]; lwr[cf] = selwv[col];
  }
  f32x4 za0q[4], za1q[4];
#pragma unroll
  for (int rf = 0; rf < 4; ++rf) {
    za0q[rf] = *(const f32x4*)&sZa0[wr * 64 + rf * 16 + r0];
    za1q[rf] = *(const f32x4*)&sZa1[wr * 64 + rf * 16 + r0];
  }
  f32x4 acc[4][4];
#pragma unroll
  for (int rf = 0; rf < 4; ++rf)
#pragma unroll
    for (int cf = 0; cf < 4; ++cf)
#pragma unroll
      for (int i = 0; i < 4; ++i)
        acc[rf][cf][i] = c0r[cf] + za0q[rf][i] * w6r[cf] + za1q[rf][i] * w7r[cf];

  const unsigned swA = (unsigned)(rA & 7) << 4;
  const unsigned gA  = (unsigned)((l >> 4) << 4);
  const char* aBase  = As_ + (wr * 64 + rA) * 512;
  const int bOff     = (wc << 12) + l16;

  // ---- GEMM1 ----
  gemm8((const char*)W1p, Bs0_, Bs1_, Bs2_, aBase, swA, gA, bOff, woff, l16, acc);

  // ---- epilogue 1: gelu -> bf16 back into A tile ----
#pragma unroll
  for (int rf = 0; rf < 4; ++rf)
#pragma unroll
    for (int i = 0; i < 4; ++i) {
      int row = wr * 64 + rf * 16 + r0 + i;
      char* rowp = As_ + row * 512;
      unsigned sw = (unsigned)(row & 7) << 4;
#pragma unroll
      for (int cf = 0; cf < 4; ++cf) {
        int col = wc * 64 + cf * 16 + rA;
        *(__bf16*)(rowp + (((unsigned)(col * 2)) ^ sw)) = (__bf16)gelu_f(acc[rf][cf][i]);
      }
    }
  // pre-stage W2 k-steps 0,1 while draining ds_writes
  stage2((const char*)W2p + woff + l16, Bs0_ + woff);
  stage2((const char*)W2p + 16384 + woff + l16, Bs1_ + woff);
  asm volatile("s_waitcnt lgkmcnt(0)" ::: "memory");  // h1 writes committed (visible after next barrier)

  // ---- GEMM2 ----
#pragma unroll
  for (int rf = 0; rf < 4; ++rf)
#pragma unroll
    for (int cf = 0; cf < 4; ++cf)
#pragma unroll
      for (int i = 0; i < 4; ++i) acc[rf][cf][i] = b2r[cf];
  gemm8((const char*)W2p, Bs0_, Bs1_, Bs2_, aBase, swA, gA, bOff, woff, l16, acc);

  // ---- epilogue 2: gelu -> logits + pooled ----
#pragma unroll
  for (int rf = 0; rf < 4; ++rf)
#pragma unroll
    for (int cf = 0; cf < 4; ++cf)
#pragma unroll
      for (int i = 0; i < 4; ++i) acc[rf][cf][i] = gelu_f(acc[rf][cf][i]);

  // selection logits: dot with sel_w, reduce over 16 col-lanes, combine 4 wc via LDS
#pragma unroll
  for (int rf = 0; rf < 4; ++rf)
#pragma unroll
    for (int i = 0; i < 4; ++i) {
      float p = acc[rf][0][i] * lwr[0] + acc[rf][1][i] * lwr[1]
              + acc[rf][2][i] * lwr[2] + acc[rf][3][i] * lwr[3];
      p += __shfl_xor(p, 1); p += __shfl_xor(p, 2);
      p += __shfl_xor(p, 4); p += __shfl_xor(p, 8);
      if (rA == 0) sLog[wr * 64 + rf * 16 + r0 + i][wc] = p;
    }
  __syncthreads();
  if (t < 128)
    outLogits[base + t] = sLog[t][0] + sLog[t][1] + sLog[t][2] + sLog[t][3]
                        + selbr + 0.5f * sFront[t];

  // pooled: segment-sum by graph
  if (sG[0] == sG[EPB - 1]) {
    int g = sG[0];
#pragma unroll
    for (int cf = 0; cf < 4; ++cf) {
      float sv = 0.f;
#pragma unroll
      for (int rf = 0; rf < 4; ++rf)
#pragma unroll
        for (int i = 0; i < 4; ++i) sv += acc[rf][cf][i];
      sv += __shfl_xor(sv, 16);
      sv += __shfl_xor(sv, 32);
      if (l < 16) atomicAdd(&pooledAcc[g * 256 + wc * 64 + cf * 16 + l], sv);
    }
  } else {  // graph-boundary block (rare): per-element atomics
#pragma unroll
    for (int rf = 0; rf < 4; ++rf)
#pragma unroll
      for (int i = 0; i < 4; ++i) {
        int row = wr * 64 + rf * 16 + r0 + i;
        int g = sG[row];
#pragma unroll
        for (int cf = 0; cf < 4; ++cf)
          atomicAdd(&pooledAcc[g * 256 + wc * 64 + cf * 16 + rA], acc[rf][cf][i]);
      }
  }
}

// ---------------------------------------------------------------------------
__global__ __launch_bounds__(256) void stop_kernel(
    const float* __restrict__ pooledAcc, const float* __restrict__ cnts,
    const float* __restrict__ qtok,
    const float* __restrict__ ln2g, const float* __restrict__ ln2b,
    const float* __restrict__ sW1, const float* __restrict__ sb1,
    const float* __restrict__ sW2, const float* __restrict__ sb2,
    float* __restrict__ outStop, float* __restrict__ outPooled) {
  __shared__ float sIn[512], sLn[512], sRed[8];
  const int t = threadIdx.x, g = blockIdx.x;
  const int w = t >> 6, l = t & 63;
  float c = fmaxf(cnts[g], 1.0f);
  float p = pooledAcc[g * 256 + t] / c;
  outPooled[g * 256 + t] = p;
  sIn[t] = p;
  sIn[256 + t] = qtok[g * 256 + t];
  __syncthreads();
  float a = sIn[t], b = sIn[256 + t];
  float s = a + b, s2 = a * a + b * b;
#pragma unroll
  for (int m = 1; m < 64; m <<= 1) { s += __shfl_xor(s, m); s2 += __shfl_xor(s2, m); }
  if (l == 0) { sRed[w] = s; sRed[4 + w] = s2; }
  __syncthreads();
  s  = sRed[0] + sRed[1] + sRed[2] + sRed[3];
  s2 = sRed[4] + sRed[5] + sRed[6] + sRed[7];
  const float mean = s * (1.0f / 512.0f);
  const float var  = s2 * (1.0f / 512.0f) - mean * mean;
  const float rstd = rsqrtf(var + 1e-5f);
  sLn[t]       = (a - mean) * rstd * ln2g[t] + ln2b[t];
  sLn[256 + t] = (b - mean) * rstd * ln2g[256 + t] + ln2b[256 + t];
  __syncthreads();
  float accv = sb1[t];
#pragma unroll 8
  for (int k = 0; k < 512; ++k) accv += sLn[k] * sW1[k * 256 + t];
  float u = gelu_f(accv);
  float part = u * sW2[t];
#pragma unroll
  for (int m = 1; m < 64; m <<= 1) part += __shfl_xor(part, m);
  if (l == 0) sRed[w] = part;
  __syncthreads();
  if (t == 0) outStop[g] = sRed[0] + sRed[1] + sRed[2] + sRed[3] + sb2[0];
}

// ---------------------------------------------------------------------------
extern "C" void kernel_launch(void* const* d_in, const int* in_sizes, int n_in,
                              void* d_out, int out_size, void* d_ws, size_t ws_size,
                              hipStream_t stream) {
  const float* tok   = (const float*)d_in[0];
  const float* qtok  = (const float*)d_in[1];
  const int* ebatch  = (const int*)d_in[2];
  const void* smask  = d_in[3];
  const int* eheads  = (const int*)d_in[4];
  const int* etails  = (const int*)d_in[5];
  const int* curtail = (const int*)d_in[6];
  const float* ln1g  = (const float*)d_in[7];
  const float* ln1b  = (const float*)d_in[8];
  const float* W1    = (const float*)d_in[9];
  const float* b1    = (const float*)d_in[10];
  const float* W2    = (const float*)d_in[11];
  const float* b2    = (const float*)d_in[12];
  const float* selw  = (const float*)d_in[13];
  const float* selb  = (const float*)d_in[14];
  const float* ln2g  = (const float*)d_in[15];
  const float* ln2b  = (const float*)d_in[16];
  const float* sW1   = (const float*)d_in[17];
  const float* sb1   = (const float*)d_in[18];
  const float* sW2   = (const float*)d_in[19];
  const float* sb2   = (const float*)d_in[20];

  const int E = in_sizes[2];            // 400000
  const int G = in_sizes[1] / 256;      // 64

  char* ws = (char*)d_ws;
  __bf16* W1p   = (__bf16*)(ws);                 // 131072 B
  __bf16* W2p   = (__bf16*)(ws + 131072);        // 131072 B
  float*  C0    = (float*)(ws + 262144);
  float*  GW6   = (float*)(ws + 263168);
  float*  GW7   = (float*)(ws + 264192);
  float*  pooled= (float*)(ws + 265216);         // 65536 B
  float*  cnts  = (float*)(ws + 330752);         // 256 B
  int*    mflag = (int*)(ws + 331008);           // 4 B
  (void)ws_size; (void)n_in; (void)out_size;

  hipMemsetAsync(ws + 265216, 0, 65536 + 256, stream);  // pooled + counts

  prep_pack<<<64, 256, 0, stream>>>(W1, W2, ln1g, W1p, W2p);
  prep_vec<<<1, 256, 0, stream>>>(W1, ln1g, ln1b, b1, (const unsigned*)smask,
                                  C0, GW6, GW7, mflag);
  edge_kernel<<<E / EPB, 512, 0, stream>>>(
      tok, ebatch, (const unsigned char*)smask, eheads, etails, curtail,
      W1p, W2p, C0, GW6, GW7, b2, selw, selb, mflag,
      (float*)d_out, pooled, cnts);
  stop_kernel<<<G, 256, 0, stream>>>(pooled, cnts, qtok, ln2g, ln2b,
                                     sW1, sb1, sW2, sb2,
                                     (float*)d_out + E, (float*)d_out + E + G);
}

// Round 3
// 350.640 us; speedup vs baseline: 1.3409x; 1.2358x over previous
//
#include <hip/hip_runtime.h>
#include <hip/hip_bf16.h>
#include <cstdint>

// EdgeFrontierPolicy: E=400000, G=64, H=256.
// M=64/block, 256 thr (4 waves, 1x4 grid, 64x64 per-wave tile), A 32KB + B dbuf
// 32KB => 67.6KB LDS => 2 blocks/CU for cross-block phase overlap.

typedef __bf16 bf16x8 __attribute__((ext_vector_type(8)));
typedef float  f32x4  __attribute__((ext_vector_type(4)));

typedef __attribute__((address_space(1))) const char gas_char;
typedef __attribute__((address_space(3))) char las_char;

// gelu tanh-form via v_exp_f32; max abs err ~5e-4 (threshold 1.03e-2).
__device__ __forceinline__ float gelu_f(float x) {
  float x2 = x * x;
  float t1 = __builtin_fmaf(0.1029444f, x2, 2.3022078f);
  float a  = x * t1;
  float e;
  asm("v_exp_f32 %0, %1" : "=v"(e) : "v"(a));
  float r;
  asm("v_rcp_f32 %0, %1" : "=v"(r) : "v"(e + 1.0f));
  return x - x * r;
}

// ---------------------------------------------------------------------------
// Pack W1 (ln1_g folded) / W2 into MFMA-B fragment order, bf16.
__global__ void prep_pack(const float* __restrict__ W1, const float* __restrict__ W2,
                          const float* __restrict__ ln1g,
                          __bf16* __restrict__ W1p, __bf16* __restrict__ W2p) {
  int gid = blockIdx.x * blockDim.x + threadIdx.x;   // 16384 threads
  int m  = gid >> 13;
  int b  = (gid >> 6) & 127;
  int l  = gid & 63;
  int kt = b >> 4, nt = b & 15;
  int k0 = kt * 32 + ((l >> 4) << 3);
  int n  = nt * 16 + (l & 15);
  const float* W = m ? W2 : W1;
  bf16x8 v;
#pragma unroll
  for (int i = 0; i < 8; ++i) {
    int k = k0 + i;
    float wv = W[k * 256 + n];
    if (!m) wv *= ln1g[k];
    v[i] = (__bf16)wv;
  }
  __bf16* dst = m ? W2p : W1p;
  *(bf16x8*)(dst + (size_t)(b * 64 + l) * 8) = v;
}

// C0/GW6/GW7 + mask dtype detect; 1024 threads, k-split 4 ways.
__global__ void prep_vec(const float* __restrict__ W1, const float* __restrict__ ln1g,
                         const float* __restrict__ ln1b, const float* __restrict__ b1,
                         const unsigned* __restrict__ smask_words,
                         float* __restrict__ C0, float* __restrict__ GW6,
                         float* __restrict__ GW7, int* __restrict__ maskIsByte) {
  __shared__ float red[4][256];
  const int n = threadIdx.x & 255, c = threadIdx.x >> 8;
  const int k0 = c * 64, k1 = (c == 3) ? 258 : k0 + 64;
  float s = 0.f;
#pragma unroll 4
  for (int k = k0; k < k1; ++k) s += ln1b[k] * W1[k * 256 + n];
  red[c][n] = s;
  __syncthreads();
  if (c == 0) {
    C0[n]  = b1[n] + red[0][n] + red[1][n] + red[2][n] + red[3][n];
    GW6[n] = ln1g[256] * W1[256 * 256 + n];
    GW7[n] = ln1g[257] * W1[257 * 256 + n];
  }
  if (threadIdx.x == 0) {
    int big = 0;
    for (int i = 0; i < 64; ++i) { if (smask_words[i] > 1u) big = 1; }
    *maskIsByte = big;
  }
}

// ---------------------------------------------------------------------------
#define EPB 64

__device__ __forceinline__ void stage4(const char* gsrc, char* ldst) {
  __builtin_amdgcn_global_load_lds((gas_char*)gsrc, (las_char*)ldst, 16, 0, 0);
  __builtin_amdgcn_global_load_lds((gas_char*)(gsrc + 1024), (las_char*)(ldst + 1024), 16, 0, 0);
  __builtin_amdgcn_global_load_lds((gas_char*)(gsrc + 2048), (las_char*)(ldst + 2048), 16, 0, 0);
  __builtin_amdgcn_global_load_lds((gas_char*)(gsrc + 3072), (las_char*)(ldst + 3072), 16, 0, 0);
}

// 8 K-steps, double-buffered B, 1 barrier/kt, counted vmcnt. Expects kt0 and
// kt1 pre-staged (queue = 8 loads). At kt7 optionally pre-stages nextWp kt0.
__device__ __forceinline__ void gemm8(const char* __restrict__ Wp, const char* nextWp,
                                      char* B0, char* B1,
                                      const char* aBase, unsigned swA, unsigned gA,
                                      int bOff, int woff, int l16, f32x4 (&acc)[4][4]) {
#pragma unroll
  for (int kt = 0; kt < 8; ++kt) {
    if (kt == 0) asm volatile("s_waitcnt vmcnt(4)" ::: "memory");
    else         asm volatile("s_waitcnt vmcnt(0)" ::: "memory");
    __builtin_amdgcn_s_barrier();
    if (kt >= 1 && kt < 7)
      stage4(Wp + (kt + 1) * 16384 + woff + l16, ((kt & 1) ? B0 : B1) + woff);
    if (kt == 7 && nextWp)
      stage4(nextWp + woff + l16, B0 + woff);   // B0's readers (kt6) done at kt7 barrier
    const char* bb = (kt & 1) ? B1 : B0;
    bf16x8 av[4], bv[4];
#pragma unroll
    for (int rf = 0; rf < 4; ++rf)
      av[rf] = *(const bf16x8*)(aBase + rf * 8192 + (((unsigned)(kt * 64) + gA) ^ swA));
#pragma unroll
    for (int cf = 0; cf < 4; ++cf)
      bv[cf] = *(const bf16x8*)(bb + bOff + (cf << 10));
#pragma unroll
    for (int rf = 0; rf < 4; ++rf)
#pragma unroll
      for (int cf = 0; cf < 4; ++cf)
        acc[rf][cf] = __builtin_amdgcn_mfma_f32_16x16x32_bf16(av[rf], bv[cf], acc[rf][cf], 0, 0, 0);
  }
  __builtin_amdgcn_s_barrier();  // all A/B reads done before caller overwrites
}

__global__ __launch_bounds__(256, 2) void edge_kernel(
    const float* __restrict__ tok, const int* __restrict__ ebatch,
    const unsigned char* __restrict__ smaskB,
    const int* __restrict__ eheads, const int* __restrict__ etails,
    const int* __restrict__ curtail,
    const __bf16* __restrict__ W1p, const __bf16* __restrict__ W2p,
    const float* __restrict__ C0v, const float* __restrict__ GW6v,
    const float* __restrict__ GW7v, const float* __restrict__ b2v,
    const float* __restrict__ selwv, const float* __restrict__ selbv,
    const int* __restrict__ maskFlag,
    float* __restrict__ outLogits, float* __restrict__ pooledAcc,
    float* __restrict__ cnts) {
  __shared__ __align__(16) char As_[64 * 512];          // 32KB, XOR-swizzled rows
  __shared__ __align__(16) char Bs_[2][16384];          // 32KB B double-buffer
  __shared__ float sZa0[64], sZa1[64], sFront[64];
  __shared__ float sLog[64][4];
  __shared__ int sG[64];

  const int t = threadIdx.x;
  const int w = t >> 6, l = t & 63;
  const int base = blockIdx.x * EPB;
  const int l16 = l << 4;
  const int woff = __builtin_amdgcn_readfirstlane(w << 12);  // wave's 4KB quarter

  const char* W1c = (const char*)W1p;
  const char* W2c = (const char*)W2p;

  // pre-stage W1 kt0,kt1 (drained before GEMM1-kt0's vmcnt(4))
  stage4(W1c + woff + l16, Bs_[0] + woff);
  stage4(W1c + 16384 + woff + l16, Bs_[1] + woff);

  // ---- flags ----
  if (t < 64) {
    int ge = base + t;
    int g  = ebatch[ge];
    int mb = *maskFlag;
    int mv = mb ? (int)smaskB[ge] : ((const int*)smaskB)[ge];
    int cand = (mv == 0);
    int cur  = curtail[g];
    int fr   = cand && ((eheads[ge] == cur) || (etails[ge] == cur));
    sZa0[t] = (float)cand; sZa1[t] = (float)fr; sFront[t] = (float)fr; sG[t] = g;
  }
  __syncthreads();

  if (t == 0) {  // counts: run-length over sorted graph ids
    int cg = sG[0]; float run = 1.f;
    for (int e = 1; e < EPB; ++e) {
      int g = sG[e];
      if (g == cg) run += 1.f;
      else { atomicAdd(&cnts[cg], run); cg = g; run = 1.f; }
    }
    atomicAdd(&cnts[cg], run);
  }

  // ---- LayerNorm over 258 (4 threads/edge), bf16 A tile, XOR-swizzled ----
  {
    const int e = t >> 2, q = t & 3;
    const float* rp = tok + (size_t)(base + e) * 256 + q * 4;
    float4 v[16];
    float s = 0.f, s2 = 0.f;
#pragma unroll
    for (int j = 0; j < 16; ++j) {
      v[j] = *(const float4*)(rp + j * 16);
      s  += v[j].x + v[j].y + v[j].z + v[j].w;
      s2 += v[j].x * v[j].x + v[j].y * v[j].y + v[j].z * v[j].z + v[j].w * v[j].w;
    }
    float a0 = 0.f, a1 = 0.f;
    if (q == 0) { a0 = sZa0[e]; a1 = sZa1[e]; s += a0 + a1; s2 += a0 + a1; }
    s  += __shfl_xor(s, 1);  s  += __shfl_xor(s, 2);
    s2 += __shfl_xor(s2, 1); s2 += __shfl_xor(s2, 2);
    const float mean = s * (1.0f / 258.0f);
    const float var  = s2 * (1.0f / 258.0f) - mean * mean;
    const float rstd = rsqrtf(var + 1e-5f);
    const unsigned sw = (unsigned)(e & 7) << 4;
#pragma unroll
    for (int j = 0; j < 16; ++j) {
      union { __bf16 h[4]; uint2 u; } cv;
      cv.h[0] = (__bf16)((v[j].x - mean) * rstd);
      cv.h[1] = (__bf16)((v[j].y - mean) * rstd);
      cv.h[2] = (__bf16)((v[j].z - mean) * rstd);
      cv.h[3] = (__bf16)((v[j].w - mean) * rstd);
      unsigned off = (unsigned)(q * 8 + j * 32);
      *(uint2*)(As_ + e * 512 + (off ^ sw)) = cv.u;
    }
    if (q == 0) {
      sZa0[e] = (a0 - mean) * rstd;
      sZa1[e] = (a1 - mean) * rstd;
    }
  }
  __syncthreads();

  // ---- per-thread constants + acc init (C0 + rank-2 aux) ----
  const int rA = l & 15;
  const int r0 = (l >> 4) << 2;
  float c0r[4], w6r[4], w7r[4], b2r[4], lwr[4];
  const float selbr = selbv[0];
#pragma unroll
  for (int cf = 0; cf < 4; ++cf) {
    int col = w * 64 + cf * 16 + rA;
    c0r[cf] = C0v[col]; w6r[cf] = GW6v[col]; w7r[cf] = GW7v[col];
    b2r[cf] = b2v[col]; lwr[cf] = selwv[col];
  }
  f32x4 za0q[4], za1q[4];
#pragma unroll
  for (int rf = 0; rf < 4; ++rf) {
    za0q[rf] = *(const f32x4*)&sZa0[rf * 16 + r0];
    za1q[rf] = *(const f32x4*)&sZa1[rf * 16 + r0];
  }
  f32x4 acc[4][4];
#pragma unroll
  for (int rf = 0; rf < 4; ++rf)
#pragma unroll
    for (int cf = 0; cf < 4; ++cf)
#pragma unroll
      for (int i = 0; i < 4; ++i)
        acc[rf][cf][i] = c0r[cf] + za0q[rf][i] * w6r[cf] + za1q[rf][i] * w7r[cf];

  const unsigned swA = (unsigned)(rA & 7) << 4;
  const unsigned gA  = (unsigned)((l >> 4) << 4);
  const char* aBase  = As_ + rA * 512;
  const int bOff     = (w << 12) + l16;

  // ---- GEMM1 (pre-stages W2-kt0 at its kt7) ----
  gemm8(W1c, W2c, Bs_[0], Bs_[1], aBase, swA, gA, bOff, woff, l16, acc);

  // ---- epilogue 1: gelu -> bf16 back into A tile ----
#pragma unroll
  for (int rf = 0; rf < 4; ++rf)
#pragma unroll
    for (int i = 0; i < 4; ++i) {
      int row = rf * 16 + r0 + i;
      char* rowp = As_ + row * 512;
      unsigned sw = (unsigned)(row & 7) << 4;
#pragma unroll
      for (int cf = 0; cf < 4; ++cf) {
        int col = w * 64 + cf * 16 + rA;
        *(__bf16*)(rowp + (((unsigned)(col * 2)) ^ sw)) = (__bf16)gelu_f(acc[rf][cf][i]);
      }
    }
  stage4(W2c + 16384 + woff + l16, Bs_[1] + woff);  // W2-kt1 (B1's kt7 readers done)
  __syncthreads();  // h1 visible; queue = [W2s0, W2s1] for GEMM2's vmcnt(4)

  // ---- GEMM2 ----
#pragma unroll
  for (int rf = 0; rf < 4; ++rf)
#pragma unroll
    for (int cf = 0; cf < 4; ++cf)
#pragma unroll
      for (int i = 0; i < 4; ++i) acc[rf][cf][i] = b2r[cf];
  gemm8(W2c, nullptr, Bs_[0], Bs_[1], aBase, swA, gA, bOff, woff, l16, acc);

  // ---- epilogue 2: gelu -> logits + pooled ----
#pragma unroll
  for (int rf = 0; rf < 4; ++rf)
#pragma unroll
    for (int cf = 0; cf < 4; ++cf)
#pragma unroll
      for (int i = 0; i < 4; ++i) acc[rf][cf][i] = gelu_f(acc[rf][cf][i]);

#pragma unroll
  for (int rf = 0; rf < 4; ++rf)
#pragma unroll
    for (int i = 0; i < 4; ++i) {
      float p = acc[rf][0][i] * lwr[0] + acc[rf][1][i] * lwr[1]
              + acc[rf][2][i] * lwr[2] + acc[rf][3][i] * lwr[3];
      p += __shfl_xor(p, 1); p += __shfl_xor(p, 2);
      p += __shfl_xor(p, 4); p += __shfl_xor(p, 8);
      if (rA == 0) sLog[rf * 16 + r0 + i][w] = p;
    }
  __syncthreads();
  if (t < 64)
    outLogits[base + t] = sLog[t][0] + sLog[t][1] + sLog[t][2] + sLog[t][3]
                        + selbr + 0.5f * sFront[t];

  if (sG[0] == sG[EPB - 1]) {
    int g = sG[0];
#pragma unroll
    for (int cf = 0; cf < 4; ++cf) {
      float sv = 0.f;
#pragma unroll
      for (int rf = 0; rf < 4; ++rf)
#pragma unroll
        for (int i = 0; i < 4; ++i) sv += acc[rf][cf][i];
      sv += __shfl_xor(sv, 16);
      sv += __shfl_xor(sv, 32);
      if (l < 16) atomicAdd(&pooledAcc[g * 256 + w * 64 + cf * 16 + l], sv);
    }
  } else {  // graph-boundary block (rare)
#pragma unroll
    for (int rf = 0; rf < 4; ++rf)
#pragma unroll
      for (int i = 0; i < 4; ++i) {
        int row = rf * 16 + r0 + i;
        int g = sG[row];
#pragma unroll
        for (int cf = 0; cf < 4; ++cf)
          atomicAdd(&pooledAcc[g * 256 + w * 64 + cf * 16 + rA], acc[rf][cf][i]);
      }
  }
}

// ---------------------------------------------------------------------------
__global__ __launch_bounds__(256) void stop_kernel(
    const float* __restrict__ pooledAcc, const float* __restrict__ cnts,
    const float* __restrict__ qtok,
    const float* __restrict__ ln2g, const float* __restrict__ ln2b,
    const float* __restrict__ sW1, const float* __restrict__ sb1,
    const float* __restrict__ sW2, const float* __restrict__ sb2,
    float* __restrict__ outStop, float* __restrict__ outPooled) {
  __shared__ float sIn[512], sLn[512], sRed[8];
  const int t = threadIdx.x, g = blockIdx.x;
  const int w = t >> 6, l = t & 63;
  float c = fmaxf(cnts[g], 1.0f);
  float p = pooledAcc[g * 256 + t] / c;
  outPooled[g * 256 + t] = p;
  sIn[t] = p;
  sIn[256 + t] = qtok[g * 256 + t];
  __syncthreads();
  float a = sIn[t], b = sIn[256 + t];
  float s = a + b, s2 = a * a + b * b;
#pragma unroll
  for (int m = 1; m < 64; m <<= 1) { s += __shfl_xor(s, m); s2 += __shfl_xor(s2, m); }
  if (l == 0) { sRed[w] = s; sRed[4 + w] = s2; }
  __syncthreads();
  s  = sRed[0] + sRed[1] + sRed[2] + sRed[3];
  s2 = sRed[4] + sRed[5] + sRed[6] + sRed[7];
  const float mean = s * (1.0f / 512.0f);
  const float var  = s2 * (1.0f / 512.0f) - mean * mean;
  const float rstd = rsqrtf(var + 1e-5f);
  sLn[t]       = (a - mean) * rstd * ln2g[t] + ln2b[t];
  sLn[256 + t] = (b - mean) * rstd * ln2g[256 + t] + ln2b[256 + t];
  __syncthreads();
  float accv = sb1[t];
#pragma unroll 8
  for (int k = 0; k < 512; ++k) accv += sLn[k] * sW1[k * 256 + t];
  float u = gelu_f(accv);
  float part = u * sW2[t];
#pragma unroll
  for (int m = 1; m < 64; m <<= 1) part += __shfl_xor(part, m);
  if (l == 0) sRed[w] = part;
  __syncthreads();
  if (t == 0) outStop[g] = sRed[0] + sRed[1] + sRed[2] + sRed[3] + sb2[0];
}

// ---------------------------------------------------------------------------
extern "C" void kernel_launch(void* const* d_in, const int* in_sizes, int n_in,
                              void* d_out, int out_size, void* d_ws, size_t ws_size,
                              hipStream_t stream) {
  const float* tok   = (const float*)d_in[0];
  const float* qtok  = (const float*)d_in[1];
  const int* ebatch  = (const int*)d_in[2];
  const void* smask  = d_in[3];
  const int* eheads  = (const int*)d_in[4];
  const int* etails  = (const int*)d_in[5];
  const int* curtail = (const int*)d_in[6];
  const float* ln1g  = (const float*)d_in[7];
  const float* ln1b  = (const float*)d_in[8];
  const float* W1    = (const float*)d_in[9];
  const float* b1    = (const float*)d_in[10];
  const float* W2    = (const float*)d_in[11];
  const float* b2    = (const float*)d_in[12];
  const float* selw  = (const float*)d_in[13];
  const float* selb  = (const float*)d_in[14];
  const float* ln2g  = (const float*)d_in[15];
  const float* ln2b  = (const float*)d_in[16];
  const float* sW1   = (const float*)d_in[17];
  const float* sb1   = (const float*)d_in[18];
  const float* sW2   = (const float*)d_in[19];
  const float* sb2   = (const float*)d_in[20];

  const int E = in_sizes[2];            // 400000
  const int G = in_sizes[1] / 256;      // 64

  char* ws = (char*)d_ws;
  __bf16* W1p   = (__bf16*)(ws);                 // 131072 B
  __bf16* W2p   = (__bf16*)(ws + 131072);        // 131072 B
  float*  C0    = (float*)(ws + 262144);
  float*  GW6   = (float*)(ws + 263168);
  float*  GW7   = (float*)(ws + 264192);
  float*  pooled= (float*)(ws + 265216);         // 65536 B
  float*  cnts  = (float*)(ws + 330752);         // 256 B
  int*    mflag = (int*)(ws + 331008);           // 4 B
  (void)ws_size; (void)n_in; (void)out_size;

  hipMemsetAsync(ws + 265216, 0, 65536 + 256, stream);  // pooled + counts

  prep_pack<<<64, 256, 0, stream>>>(W1, W2, ln1g, W1p, W2p);
  prep_vec<<<1, 1024, 0, stream>>>(W1, ln1g, ln1b, b1, (const unsigned*)smask,
                                   C0, GW6, GW7, mflag);
  edge_kernel<<<E / EPB, 256, 0, stream>>>(
      tok, ebatch, (const unsigned char*)smask, eheads, etails, curtail,
      W1p, W2p, C0, GW6, GW7, b2, selw, selb, mflag,
      (float*)d_out, pooled, cnts);
  stop_kernel<<<G, 256, 0, stream>>>(pooled, cnts, qtok, ln2g, ln2b,
                                     sW1, sb1, sW2, sb2,
                                     (float*)d_out + E, (float*)d_out + E + G);
}